// Round 1
// baseline (4803.448 us; speedup 1.0000x reference)
//
#include <hip/hip_runtime.h>
#include <math.h>

#define D 128

// ---------------- degree / normalization ----------------

__global__ void k_init_deg(float* __restrict__ deg, int N) {
    int i = blockIdx.x * blockDim.x + threadIdx.x;
    if (i < N) deg[i] = 1.0f;  // self-loop
}

__global__ void k_deg_edges(const int* __restrict__ ei, float* __restrict__ deg, int E) {
    int e = blockIdx.x * blockDim.x + threadIdx.x;
    if (e < E) atomicAdd(&deg[ei[E + e]], 1.0f);  // dst row of edge_index
}

__global__ void k_rsqrt_inplace(float* __restrict__ deg, int N) {
    int i = blockIdx.x * blockDim.x + threadIdx.x;
    if (i < N) deg[i] = rsqrtf(deg[i]);  // deg >= 1 always (self-loops)
}

// ---------------- GEMM: hws = (H @ W) * dinv[row]; acc = hws (self-loop init) ----------------
// Tile: 64 rows x 128 cols, 256 threads, thread = 4x8 micro-tile.

__global__ __launch_bounds__(256) void k_gemm_scale(
        const float* __restrict__ H, const float* __restrict__ W,
        const float* __restrict__ dinv, float* __restrict__ hws,
        float* __restrict__ acc, int N) {
    __shared__ float As[64][20];   // stride 20: keeps float4 stores 16B-aligned, breaks bank aliasing
    __shared__ float Bs[16][128];

    const int tid = threadIdx.x;
    const int tx = tid & 15;       // 0..15 -> col group (8 cols)
    const int ty = tid >> 4;       // 0..15 -> row group (4 rows)
    const int row0 = blockIdx.x * 64;

    float c[4][8];
#pragma unroll
    for (int i = 0; i < 4; i++)
#pragma unroll
        for (int j = 0; j < 8; j++) c[i][j] = 0.0f;

    for (int k0 = 0; k0 < D; k0 += 16) {
        // A tile: 64 rows x 16 k  (one float4 per thread)
        {
            int ar = tid >> 2;
            int ak = (tid & 3) * 4;
            int gr = row0 + ar;
            float4 av = make_float4(0.f, 0.f, 0.f, 0.f);
            if (gr < N) av = *(const float4*)(H + (size_t)gr * D + k0 + ak);
            *(float4*)(&As[ar][ak]) = av;
        }
        // B tile: 16 k x 128 cols (two float4 per thread)
#pragma unroll
        for (int i = 0; i < 2; i++) {
            int idx = tid + i * 256;         // 0..511
            int bk = idx >> 5;               // 0..15
            int bc = (idx & 31) * 4;         // 0..124
            *(float4*)(&Bs[bk][bc]) = *(const float4*)(W + (size_t)(k0 + bk) * D + bc);
        }
        __syncthreads();

#pragma unroll
        for (int kk = 0; kk < 16; kk++) {
            float a0 = As[ty * 4 + 0][kk];
            float a1 = As[ty * 4 + 1][kk];
            float a2 = As[ty * 4 + 2][kk];
            float a3 = As[ty * 4 + 3][kk];
            float4 b0 = *(float4*)(&Bs[kk][tx * 8]);
            float4 b1 = *(float4*)(&Bs[kk][tx * 8 + 4]);
            const float bb[8] = {b0.x, b0.y, b0.z, b0.w, b1.x, b1.y, b1.z, b1.w};
            const float aa[4] = {a0, a1, a2, a3};
#pragma unroll
            for (int i = 0; i < 4; i++)
#pragma unroll
                for (int j = 0; j < 8; j++)
                    c[i][j] = fmaf(aa[i], bb[j], c[i][j]);
        }
        __syncthreads();
    }

#pragma unroll
    for (int i = 0; i < 4; i++) {
        int gr = row0 + ty * 4 + i;
        if (gr >= N) continue;
        float s = dinv[gr];
        float4 o0 = make_float4(c[i][0] * s, c[i][1] * s, c[i][2] * s, c[i][3] * s);
        float4 o1 = make_float4(c[i][4] * s, c[i][5] * s, c[i][6] * s, c[i][7] * s);
        size_t base = (size_t)gr * D + tx * 8;
        *(float4*)(hws + base)     = o0;
        *(float4*)(hws + base + 4) = o1;
        *(float4*)(acc + base)     = o0;   // self-loop term initializes accumulator
        *(float4*)(acc + base + 4) = o1;
    }
}

// ---------------- edge scatter: acc[dst] += hws[src]  (32 threads / edge) ----------------

__global__ __launch_bounds__(256) void k_edge_scatter(
        const int* __restrict__ ei, const float* __restrict__ hws,
        float* __restrict__ acc, int E) {
    int gt = blockIdx.x * blockDim.x + threadIdx.x;
    int e = gt >> 5;
    if (e >= E) return;
    int lane = gt & 31;
    int src = ei[e];
    int dst = ei[E + e];
    float4 v = *(const float4*)(hws + (size_t)src * D + lane * 4);
    float* p = acc + (size_t)dst * D + lane * 4;
    atomicAdd(p + 0, v.x);
    atomicAdd(p + 1, v.y);
    atomicAdd(p + 2, v.z);
    atomicAdd(p + 3, v.w);
}

// ---------------- finalize: h = relu(dinv[row] * acc + bias), in place ----------------

__global__ __launch_bounds__(256) void k_finalize(
        float* __restrict__ acc, const float* __restrict__ dinv,
        const float* __restrict__ bias, int N) {
    int idx = blockIdx.x * blockDim.x + threadIdx.x;   // one float4 per thread
    int total = N * (D / 4);
    if (idx >= total) return;
    int row = idx >> 5;
    int c4 = (idx & 31) * 4;
    float s = dinv[row];
    float4 v = *(float4*)(acc + (size_t)row * D + c4);
    const float4 b = *(const float4*)(bias + c4);
    v.x = fmaxf(fmaf(s, v.x, b.x), 0.f);
    v.y = fmaxf(fmaf(s, v.y, b.y), 0.f);
    v.z = fmaxf(fmaf(s, v.z, b.z), 0.f);
    v.w = fmaxf(fmaf(s, v.w, b.w), 0.f);
    *(float4*)(acc + (size_t)row * D + c4) = v;
}

// ---------------- pooling (batch is sorted): running per-segment sums ----------------

#define POOL_ROWS 256

__global__ __launch_bounds__(128) void k_zero(float* __restrict__ p, int n) {
    int i = blockIdx.x * blockDim.x + threadIdx.x;
    if (i < n) p[i] = 0.f;
}

__global__ __launch_bounds__(128) void k_pool(
        const float* __restrict__ h, const int* __restrict__ batch,
        float* __restrict__ pooled, int N) {
    int c = threadIdx.x;                       // column 0..127
    int r0 = blockIdx.x * POOL_ROWS;
    if (r0 >= N) return;
    int rend = r0 + POOL_ROWS;
    if (rend > N) rend = N;
    int cur = batch[r0];
    float a = 0.f;
    for (int r = r0; r < rend; r++) {
        int b = batch[r];                      // uniform across block -> broadcast
        if (b != cur) {
            atomicAdd(&pooled[(size_t)cur * D + c], a);
            cur = b;
            a = 0.f;
        }
        a += h[(size_t)r * D + c];
    }
    atomicAdd(&pooled[(size_t)cur * D + c], a);
}

// ---------------- MLP head: one block per graph ----------------

__global__ __launch_bounds__(128) void k_head(
        const float* __restrict__ pooled,
        const float* __restrict__ W1, const float* __restrict__ b1,
        const float* __restrict__ W2, const float* __restrict__ b2,
        const float* __restrict__ W3, const float* __restrict__ b3,
        float* __restrict__ out) {
    __shared__ float v[D];
    __shared__ float z[D];
    __shared__ float red[D];
    int g = blockIdx.x;
    int t = threadIdx.x;

    v[t] = pooled[(size_t)g * D + t];
    __syncthreads();

    float s = b1[t];
    for (int k = 0; k < D; k++) s = fmaf(v[k], W1[(size_t)k * D + t], s);
    z[t] = fmaxf(s, 0.f);
    __syncthreads();

    s = b2[t];
    for (int k = 0; k < D; k++) s = fmaf(z[k], W2[(size_t)k * D + t], s);
    float z2 = fmaxf(s, 0.f);

    red[t] = z2 * W3[t];
    __syncthreads();
    for (int off = 64; off >= 1; off >>= 1) {
        if (t < off) red[t] += red[t + off];
        __syncthreads();
    }
    if (t == 0) out[g] = 1.f / (1.f + expf(-(red[0] + b3[0])));
}

// ---------------- orchestration ----------------

extern "C" void kernel_launch(void* const* d_in, const int* in_sizes, int n_in,
                              void* d_out, int out_size, void* d_ws, size_t ws_size,
                              hipStream_t stream) {
    const float* x     = (const float*)d_in[0];
    const int*   ei    = (const int*)d_in[1];    // [2][E]: row0=src, row1=dst
    const int*   batch = (const int*)d_in[2];
    const float* convW = (const float*)d_in[3];  // [4][128][128]
    const float* convB = (const float*)d_in[4];  // [4][128]
    const float* W1 = (const float*)d_in[5];
    const float* b1 = (const float*)d_in[6];
    const float* W2 = (const float*)d_in[7];
    const float* b2 = (const float*)d_in[8];
    const float* W3 = (const float*)d_in[9];
    const float* b3 = (const float*)d_in[10];
    float* out = (float*)d_out;

    const int N = in_sizes[0] / D;          // 100000
    const int E = in_sizes[1] / 2;          // 640000
    const int G = out_size;                 // 512

    // workspace layout (floats)
    float* ws = (float*)d_ws;
    size_t off = 0;
    float* dinv = ws + off;  off += (size_t)((N + 1023) / 1024) * 1024;
    float* hws  = ws + off;  off += (size_t)N * D;
    float* bufA = ws + off;  off += (size_t)N * D;
    float* bufB = ws + off;  off += (size_t)N * D;
    float* pooled = ws + off; off += (size_t)G * D;

    // degrees -> dinv
    k_init_deg<<<(N + 255) / 256, 256, 0, stream>>>(dinv, N);
    k_deg_edges<<<(E + 255) / 256, 256, 0, stream>>>(ei, dinv, E);
    k_rsqrt_inplace<<<(N + 255) / 256, 256, 0, stream>>>(dinv, N);

    const float* hin = x;
    float* accbuf[4] = {bufA, bufB, bufA, bufB};
    const int gemm_grid = (N + 63) / 64;
    const int scat_grid = (E * 32 + 255) / 256;
    const int fin_grid  = (N * (D / 4) + 255) / 256;

    for (int l = 0; l < 4; l++) {
        float* acc = accbuf[l];
        k_gemm_scale<<<gemm_grid, 256, 0, stream>>>(hin, convW + (size_t)l * D * D,
                                                    dinv, hws, acc, N);
        k_edge_scatter<<<scat_grid, 256, 0, stream>>>(ei, hws, acc, E);
        k_finalize<<<fin_grid, 256, 0, stream>>>(acc, dinv, convB + (size_t)l * D, N);
        hin = acc;
    }

    // pooling
    k_zero<<<(G * D + 127) / 128, 128, 0, stream>>>(pooled, G * D);
    k_pool<<<(N + POOL_ROWS - 1) / POOL_ROWS, 128, 0, stream>>>(hin, batch, pooled, N);

    // head
    k_head<<<G, 128, 0, stream>>>(pooled, W1, b1, W2, b2, W3, b3, out);
}

// Round 2
// 779.534 us; speedup vs baseline: 6.1619x; 6.1619x over previous
//
#include <hip/hip_runtime.h>
#include <math.h>

#define D 128

// ================= CSR build (counting sort by dst) =================

__global__ void k_zero_int(int* __restrict__ p, int n) {
    int i = blockIdx.x * blockDim.x + threadIdx.x;
    if (i < n) p[i] = 0;
}

__global__ void k_count(const int* __restrict__ ei, int* __restrict__ counts, int E) {
    int e = blockIdx.x * blockDim.x + threadIdx.x;
    if (e < E) atomicAdd(&counts[ei[E + e]], 1);   // dst row
}

__global__ void k_dinv(const int* __restrict__ counts, float* __restrict__ dinv, int N) {
    int i = blockIdx.x * blockDim.x + threadIdx.x;
    if (i < N) dinv[i] = rsqrtf((float)(counts[i] + 1));  // +1 self-loop
}

// ---- exclusive scan over counts[N] -> rowptr[N+1], 1024 elems/block ----

__global__ __launch_bounds__(256) void k_scan1(const int* __restrict__ counts,
                                               int* __restrict__ rowptr,
                                               int* __restrict__ bsums, int N) {
    __shared__ int sh[256];
    const int t = threadIdx.x;
    const int base = blockIdx.x * 1024 + t * 4;
    int c[4];
#pragma unroll
    for (int j = 0; j < 4; j++) c[j] = (base + j < N) ? counts[base + j] : 0;
    int tsum = c[0] + c[1] + c[2] + c[3];
    sh[t] = tsum;
    __syncthreads();
    for (int off = 1; off < 256; off <<= 1) {
        int v = (t >= off) ? sh[t - off] : 0;
        __syncthreads();
        sh[t] += v;
        __syncthreads();
    }
    int run = (t == 0) ? 0 : sh[t - 1];
    if (t == 255) bsums[blockIdx.x] = sh[255];
#pragma unroll
    for (int j = 0; j < 4; j++) {
        if (base + j <= N) rowptr[base + j] = run;
        run += c[j];
    }
}

__global__ __launch_bounds__(128) void k_scan2(int* __restrict__ bsums, int NB) {
    __shared__ int sh[128];
    const int t = threadIdx.x;
    sh[t] = (t < NB) ? bsums[t] : 0;
    __syncthreads();
    for (int off = 1; off < 128; off <<= 1) {
        int v = (t >= off) ? sh[t - off] : 0;
        __syncthreads();
        sh[t] += v;
        __syncthreads();
    }
    if (t < NB) bsums[t] = (t == 0) ? 0 : sh[t - 1];
}

__global__ void k_scan3(int* __restrict__ rowptr, const int* __restrict__ bsums, int N) {
    int i = blockIdx.x * blockDim.x + threadIdx.x;
    if (i <= N) rowptr[i] += bsums[i >> 10];
}

__global__ void k_fill(const int* __restrict__ ei, int* __restrict__ cursor,
                       int* __restrict__ srcs, int E) {
    int e = blockIdx.x * blockDim.x + threadIdx.x;
    if (e >= E) return;
    int pos = atomicAdd(&cursor[ei[E + e]], 1);
    srcs[pos] = ei[e];
}

// ================= GEMM: hws = (H @ W) * dinv[row] =================
// Tile: 64 rows x 128 cols, 256 threads, thread = 4x8 micro-tile.

__global__ __launch_bounds__(256) void k_gemm_scale(
        const float* __restrict__ H, const float* __restrict__ W,
        const float* __restrict__ dinv, float* __restrict__ hws, int N) {
    __shared__ float As[64][20];
    __shared__ float Bs[16][128];

    const int tid = threadIdx.x;
    const int tx = tid & 15;
    const int ty = tid >> 4;
    const int row0 = blockIdx.x * 64;

    float c[4][8];
#pragma unroll
    for (int i = 0; i < 4; i++)
#pragma unroll
        for (int j = 0; j < 8; j++) c[i][j] = 0.0f;

    for (int k0 = 0; k0 < D; k0 += 16) {
        {
            int ar = tid >> 2;
            int ak = (tid & 3) * 4;
            int gr = row0 + ar;
            float4 av = make_float4(0.f, 0.f, 0.f, 0.f);
            if (gr < N) av = *(const float4*)(H + (size_t)gr * D + k0 + ak);
            *(float4*)(&As[ar][ak]) = av;
        }
#pragma unroll
        for (int i = 0; i < 2; i++) {
            int idx = tid + i * 256;
            int bk = idx >> 5;
            int bc = (idx & 31) * 4;
            *(float4*)(&Bs[bk][bc]) = *(const float4*)(W + (size_t)(k0 + bk) * D + bc);
        }
        __syncthreads();

#pragma unroll
        for (int kk = 0; kk < 16; kk++) {
            float a0 = As[ty * 4 + 0][kk];
            float a1 = As[ty * 4 + 1][kk];
            float a2 = As[ty * 4 + 2][kk];
            float a3 = As[ty * 4 + 3][kk];
            float4 b0 = *(float4*)(&Bs[kk][tx * 8]);
            float4 b1 = *(float4*)(&Bs[kk][tx * 8 + 4]);
            const float bb[8] = {b0.x, b0.y, b0.z, b0.w, b1.x, b1.y, b1.z, b1.w};
            const float aa[4] = {a0, a1, a2, a3};
#pragma unroll
            for (int i = 0; i < 4; i++)
#pragma unroll
                for (int j = 0; j < 8; j++)
                    c[i][j] = fmaf(aa[i], bb[j], c[i][j]);
        }
        __syncthreads();
    }

#pragma unroll
    for (int i = 0; i < 4; i++) {
        int gr = row0 + ty * 4 + i;
        if (gr >= N) continue;
        float s = dinv[gr];
        float4 o0 = make_float4(c[i][0] * s, c[i][1] * s, c[i][2] * s, c[i][3] * s);
        float4 o1 = make_float4(c[i][4] * s, c[i][5] * s, c[i][6] * s, c[i][7] * s);
        size_t base = (size_t)gr * D + tx * 8;
        *(float4*)(hws + base)     = o0;
        *(float4*)(hws + base + 4) = o1;
    }
}

// ====== aggregation: one wave per node, segmented sum, fused finalize ======
// hout[i] = relu(dinv[i] * (hws[i] + sum_{e in row i} hws[srcs[e]]) + bias)

__global__ __launch_bounds__(256) void k_agg(
        const int* __restrict__ rowptr, const int* __restrict__ srcs,
        const float* __restrict__ hws, const float* __restrict__ dinv,
        const float* __restrict__ bias, float* __restrict__ hout, int N) {
    int wid = (blockIdx.x * blockDim.x + threadIdx.x) >> 6;   // node index
    if (wid >= N) return;
    int lane = threadIdx.x & 63;
    int c = lane * 2;

    int beg = rowptr[wid];
    int end = rowptr[wid + 1];

    float2 acc = *(const float2*)(hws + (size_t)wid * D + c);  // self-loop term
    for (int e = beg; e < end; e++) {
        int s = srcs[e];
        float2 v = *(const float2*)(hws + (size_t)s * D + c);
        acc.x += v.x;
        acc.y += v.y;
    }
    float sc = dinv[wid];
    float2 b = *(const float2*)(bias + c);
    float2 o;
    o.x = fmaxf(fmaf(sc, acc.x, b.x), 0.f);
    o.y = fmaxf(fmaf(sc, acc.y, b.y), 0.f);
    *(float2*)(hout + (size_t)wid * D + c) = o;
}

// ================= pooling (batch sorted) =================

#define POOL_ROWS 256

__global__ __launch_bounds__(128) void k_zero(float* __restrict__ p, int n) {
    int i = blockIdx.x * blockDim.x + threadIdx.x;
    if (i < n) p[i] = 0.f;
}

__global__ __launch_bounds__(128) void k_pool(
        const float* __restrict__ h, const int* __restrict__ batch,
        float* __restrict__ pooled, int N) {
    int c = threadIdx.x;
    int r0 = blockIdx.x * POOL_ROWS;
    if (r0 >= N) return;
    int rend = r0 + POOL_ROWS;
    if (rend > N) rend = N;
    int cur = batch[r0];
    float a = 0.f;
    for (int r = r0; r < rend; r++) {
        int b = batch[r];
        if (b != cur) {
            atomicAdd(&pooled[(size_t)cur * D + c], a);
            cur = b;
            a = 0.f;
        }
        a += h[(size_t)r * D + c];
    }
    atomicAdd(&pooled[(size_t)cur * D + c], a);
}

// ================= MLP head =================

__global__ __launch_bounds__(128) void k_head(
        const float* __restrict__ pooled,
        const float* __restrict__ W1, const float* __restrict__ b1,
        const float* __restrict__ W2, const float* __restrict__ b2,
        const float* __restrict__ W3, const float* __restrict__ b3,
        float* __restrict__ out) {
    __shared__ float v[D];
    __shared__ float z[D];
    __shared__ float red[D];
    int g = blockIdx.x;
    int t = threadIdx.x;

    v[t] = pooled[(size_t)g * D + t];
    __syncthreads();

    float s = b1[t];
    for (int k = 0; k < D; k++) s = fmaf(v[k], W1[(size_t)k * D + t], s);
    z[t] = fmaxf(s, 0.f);
    __syncthreads();

    s = b2[t];
    for (int k = 0; k < D; k++) s = fmaf(z[k], W2[(size_t)k * D + t], s);
    float z2 = fmaxf(s, 0.f);

    red[t] = z2 * W3[t];
    __syncthreads();
    for (int off = 64; off >= 1; off >>= 1) {
        if (t < off) red[t] += red[t + off];
        __syncthreads();
    }
    if (t == 0) out[g] = 1.f / (1.f + expf(-(red[0] + b3[0])));
}

// ================= orchestration =================

extern "C" void kernel_launch(void* const* d_in, const int* in_sizes, int n_in,
                              void* d_out, int out_size, void* d_ws, size_t ws_size,
                              hipStream_t stream) {
    const float* x     = (const float*)d_in[0];
    const int*   ei    = (const int*)d_in[1];
    const int*   batch = (const int*)d_in[2];
    const float* convW = (const float*)d_in[3];
    const float* convB = (const float*)d_in[4];
    const float* W1 = (const float*)d_in[5];
    const float* b1 = (const float*)d_in[6];
    const float* W2 = (const float*)d_in[7];
    const float* b2 = (const float*)d_in[8];
    const float* W3 = (const float*)d_in[9];
    const float* b3 = (const float*)d_in[10];
    float* out = (float*)d_out;

    const int N = in_sizes[0] / D;          // 100000
    const int E = in_sizes[1] / 2;          // 640000
    const int G = out_size;                 // 512
    const int NB = (N + 1023) / 1024;       // scan blocks

    // ---- workspace layout (256B-aligned chunks) ----
    char* w = (char*)d_ws;
    size_t off = 0;
    auto alloc = [&](size_t bytes) -> char* {
        char* p = w + off;
        off += (bytes + 255) & ~(size_t)255;
        return p;
    };
    float* dinv   = (float*)alloc((size_t)N * 4);
    float* hws    = (float*)alloc((size_t)N * D * 4);
    float* bufA   = (float*)alloc((size_t)N * D * 4);
    float* pooled = (float*)alloc((size_t)G * D * 4);
    int*   counts = (int*)alloc((size_t)N * 4);
    int*   rowptr = (int*)alloc((size_t)(N + 1) * 4);
    int*   cursor = (int*)alloc((size_t)N * 4);
    int*   srcs   = (int*)alloc((size_t)E * 4);
    int*   bsums  = (int*)alloc((size_t)NB * 4);

    // ---- CSR build ----
    k_zero_int<<<(N + 255) / 256, 256, 0, stream>>>(counts, N);
    k_count<<<(E + 255) / 256, 256, 0, stream>>>(ei, counts, E);
    k_dinv<<<(N + 255) / 256, 256, 0, stream>>>(counts, dinv, N);
    k_scan1<<<NB, 256, 0, stream>>>(counts, rowptr, bsums, N);
    k_scan2<<<1, 128, 0, stream>>>(bsums, NB);
    k_scan3<<<(N + 1 + 255) / 256, 256, 0, stream>>>(rowptr, bsums, N);
    hipMemcpyAsync(cursor, rowptr, (size_t)N * 4, hipMemcpyDeviceToDevice, stream);
    k_fill<<<(E + 255) / 256, 256, 0, stream>>>(ei, cursor, srcs, E);

    // ---- 4 GCN layers ----
    const int gemm_grid = (N + 63) / 64;
    const int agg_grid  = (N + 3) / 4;      // 4 waves (nodes) per 256-thread block

    const float* hin = x;
    for (int l = 0; l < 4; l++) {
        k_gemm_scale<<<gemm_grid, 256, 0, stream>>>(hin, convW + (size_t)l * D * D,
                                                    dinv, hws, N);
        k_agg<<<agg_grid, 256, 0, stream>>>(rowptr, srcs, hws, dinv,
                                            convB + (size_t)l * D, bufA, N);
        hin = bufA;
    }

    // ---- pooling + head ----
    k_zero<<<(G * D + 127) / 128, 128, 0, stream>>>(pooled, G * D);
    k_pool<<<(N + POOL_ROWS - 1) / POOL_ROWS, 128, 0, stream>>>(hin, batch, pooled, N);
    k_head<<<G, 128, 0, stream>>>(pooled, W1, b1, W2, b2, W3, b3, out);
}

// Round 3
// 636.124 us; speedup vs baseline: 7.5511x; 1.2254x over previous
//
#include <hip/hip_runtime.h>
#include <math.h>

#define D 128

typedef _Float16 half8 __attribute__((ext_vector_type(8)));
typedef float f32x4 __attribute__((ext_vector_type(4)));

// ================= CSR build (counting sort by dst) =================

__global__ void k_zero_int(int* __restrict__ p, int n) {
    int i = blockIdx.x * blockDim.x + threadIdx.x;
    if (i < n) p[i] = 0;
}

__global__ void k_count(const int* __restrict__ ei, int* __restrict__ counts, int E) {
    int e = blockIdx.x * blockDim.x + threadIdx.x;
    if (e < E) atomicAdd(&counts[ei[E + e]], 1);   // dst row
}

__global__ void k_dinv(const int* __restrict__ counts, float* __restrict__ dinv, int N) {
    int i = blockIdx.x * blockDim.x + threadIdx.x;
    if (i < N) dinv[i] = rsqrtf((float)(counts[i] + 1));  // +1 self-loop
}

__global__ __launch_bounds__(256) void k_scan1(const int* __restrict__ counts,
                                               int* __restrict__ rowptr,
                                               int* __restrict__ bsums, int N) {
    __shared__ int sh[256];
    const int t = threadIdx.x;
    const int base = blockIdx.x * 1024 + t * 4;
    int c[4];
#pragma unroll
    for (int j = 0; j < 4; j++) c[j] = (base + j < N) ? counts[base + j] : 0;
    int tsum = c[0] + c[1] + c[2] + c[3];
    sh[t] = tsum;
    __syncthreads();
    for (int off = 1; off < 256; off <<= 1) {
        int v = (t >= off) ? sh[t - off] : 0;
        __syncthreads();
        sh[t] += v;
        __syncthreads();
    }
    int run = (t == 0) ? 0 : sh[t - 1];
    if (t == 255) bsums[blockIdx.x] = sh[255];
#pragma unroll
    for (int j = 0; j < 4; j++) {
        if (base + j <= N) rowptr[base + j] = run;
        run += c[j];
    }
}

__global__ __launch_bounds__(128) void k_scan2(int* __restrict__ bsums, int NB) {
    __shared__ int sh[128];
    const int t = threadIdx.x;
    sh[t] = (t < NB) ? bsums[t] : 0;
    __syncthreads();
    for (int off = 1; off < 128; off <<= 1) {
        int v = (t >= off) ? sh[t - off] : 0;
        __syncthreads();
        sh[t] += v;
        __syncthreads();
    }
    if (t < NB) bsums[t] = (t == 0) ? 0 : sh[t - 1];
}

__global__ void k_scan3(int* __restrict__ rowptr, const int* __restrict__ bsums, int N) {
    int i = blockIdx.x * blockDim.x + threadIdx.x;
    if (i <= N) rowptr[i] += bsums[i >> 10];
}

__global__ void k_fill(const int* __restrict__ ei, int* __restrict__ cursor,
                       int* __restrict__ srcs, int E) {
    int e = blockIdx.x * blockDim.x + threadIdx.x;
    if (e >= E) return;
    int pos = atomicAdd(&cursor[ei[E + e]], 1);
    srcs[pos] = ei[e];
}

// ================= GEMM: hws = (H @ W) * dinv[row], split-fp16 MFMA =================
// Block: 256 thr (4 waves), M-tile 128 (wave = 32 rows = 2x 16-row MFMA tiles, 8 col-tiles).
// D = Ahi*Bhi + Ahi*Blo + Alo*Bhi  (fp32 accumulate) ~= fp32 exact (rel err ~2^-22).
// B staged once/block into LDS in fragment-packed order -> conflict-free ds_read_b128.

__global__ __launch_bounds__(256) void k_gemm_mfma(
        const float* __restrict__ H, const float* __restrict__ W,
        const float* __restrict__ dinv, float* __restrict__ hws, int N) {
    __shared__ _Float16 Bhi[32 * 64 * 8];   // 32 KB: 32 packs (s,c) x 64 lanes x 8 halves
    __shared__ _Float16 Blo[32 * 64 * 8];   // 32 KB

    const int tid  = threadIdx.x;
    const int w    = tid >> 6;        // wave 0..3
    const int lane = tid & 63;
    const int q    = lane >> 4;       // quad 0..3
    const int l16  = lane & 15;
    const int row0 = blockIdx.x * 128;

    // ---- stage B (fragment-packed, hi/lo split) ----
    for (int slot = tid; slot < 32 * 64; slot += 256) {
        int p = slot >> 6, l = slot & 63;
        int s = p >> 3, c = p & 7;
        int kbase = s * 32 + ((l >> 4) << 3);
        int n = (c << 4) + (l & 15);
        half8 hv, lv;
#pragma unroll
        for (int j = 0; j < 8; j++) {
            float wv = W[(size_t)(kbase + j) * D + n];
            _Float16 h = (_Float16)wv;
            hv[j] = h;
            lv[j] = (_Float16)(wv - (float)h);
        }
        *(half8*)(&Bhi[slot * 8]) = hv;
        *(half8*)(&Blo[slot * 8]) = lv;
    }
    __syncthreads();

    f32x4 acc[2][8];
#pragma unroll
    for (int t = 0; t < 2; t++)
#pragma unroll
        for (int c = 0; c < 8; c++) acc[t][c] = (f32x4){0.f, 0.f, 0.f, 0.f};

    const int rb0 = row0 + w * 32;

#pragma unroll
    for (int s = 0; s < 4; s++) {
        // A fragments for 2 row-tiles: row = rb0 + t*16 + l16, k = s*32 + q*8 + j
        half8 ah[2], al[2];
#pragma unroll
        for (int t = 0; t < 2; t++) {
            int row = rb0 + t * 16 + l16;
            int rowc = row < N ? row : N - 1;
            const float* ap = H + (size_t)rowc * D + s * 32 + q * 8;
            float4 v0 = *(const float4*)(ap);
            float4 v1 = *(const float4*)(ap + 4);
            const float vv[8] = {v0.x, v0.y, v0.z, v0.w, v1.x, v1.y, v1.z, v1.w};
#pragma unroll
            for (int j = 0; j < 8; j++) {
                _Float16 h = (_Float16)vv[j];
                ah[t][j] = h;
                al[t][j] = (_Float16)(vv[j] - (float)h);
            }
        }
#pragma unroll
        for (int c = 0; c < 8; c++) {
            const int pb = ((s << 3) + c) * 512 + lane * 8;
            half8 bh = *(half8*)(&Bhi[pb]);
            half8 bl = *(half8*)(&Blo[pb]);
#pragma unroll
            for (int t = 0; t < 2; t++) {
                acc[t][c] = __builtin_amdgcn_mfma_f32_16x16x32_f16(al[t], bh, acc[t][c], 0, 0, 0);
                acc[t][c] = __builtin_amdgcn_mfma_f32_16x16x32_f16(ah[t], bl, acc[t][c], 0, 0, 0);
                acc[t][c] = __builtin_amdgcn_mfma_f32_16x16x32_f16(ah[t], bh, acc[t][c], 0, 0, 0);
            }
        }
    }

    // ---- epilogue: scale by dinv[row], store. C/D: col=l16, row=q*4+reg ----
    float dv[2][4];
#pragma unroll
    for (int t = 0; t < 2; t++)
#pragma unroll
        for (int r = 0; r < 4; r++) {
            int row = rb0 + t * 16 + q * 4 + r;
            dv[t][r] = (row < N) ? dinv[row] : 0.f;
        }
#pragma unroll
    for (int t = 0; t < 2; t++) {
        int rbase = rb0 + t * 16 + q * 4;
#pragma unroll
        for (int c = 0; c < 8; c++) {
            int col = c * 16 + l16;
#pragma unroll
            for (int r = 0; r < 4; r++) {
                int row = rbase + r;
                if (row < N) hws[(size_t)row * D + col] = acc[t][c][r] * dv[t][r];
            }
        }
    }
}

// ====== aggregation: one wave per node, segmented sum, fused finalize ======
// hout[i] = relu(dinv[i] * (hws[i] + sum_{e in row i} hws[srcs[e]]) + bias)

__global__ __launch_bounds__(256) void k_agg(
        const int* __restrict__ rowptr, const int* __restrict__ srcs,
        const float* __restrict__ hws, const float* __restrict__ dinv,
        const float* __restrict__ bias, float* __restrict__ hout, int N) {
    int wid = (blockIdx.x * blockDim.x + threadIdx.x) >> 6;   // node index
    if (wid >= N) return;
    int lane = threadIdx.x & 63;
    int c = lane * 2;

    int beg = rowptr[wid];
    int end = rowptr[wid + 1];

    float2 a0 = *(const float2*)(hws + (size_t)wid * D + c);  // self-loop term
    float2 a1 = make_float2(0.f, 0.f);
    float2 a2 = make_float2(0.f, 0.f);
    float2 a3 = make_float2(0.f, 0.f);

    int e = beg;
    for (; e + 4 <= end; e += 4) {
        int s0 = srcs[e], s1 = srcs[e + 1], s2 = srcs[e + 2], s3 = srcs[e + 3];
        float2 v0 = *(const float2*)(hws + (size_t)s0 * D + c);
        float2 v1 = *(const float2*)(hws + (size_t)s1 * D + c);
        float2 v2 = *(const float2*)(hws + (size_t)s2 * D + c);
        float2 v3 = *(const float2*)(hws + (size_t)s3 * D + c);
        a0.x += v0.x; a0.y += v0.y;
        a1.x += v1.x; a1.y += v1.y;
        a2.x += v2.x; a2.y += v2.y;
        a3.x += v3.x; a3.y += v3.y;
    }
    for (; e < end; e++) {
        int s = srcs[e];
        float2 v = *(const float2*)(hws + (size_t)s * D + c);
        a0.x += v.x; a0.y += v.y;
    }
    a0.x += a1.x + a2.x + a3.x;
    a0.y += a1.y + a2.y + a3.y;

    float sc = dinv[wid];
    float2 b = *(const float2*)(bias + c);
    float2 o;
    o.x = fmaxf(fmaf(sc, a0.x, b.x), 0.f);
    o.y = fmaxf(fmaf(sc, a0.y, b.y), 0.f);
    *(float2*)(hout + (size_t)wid * D + c) = o;
}

// ================= pooling (batch sorted) =================

#define POOL_ROWS 256

__global__ __launch_bounds__(128) void k_zero(float* __restrict__ p, int n) {
    int i = blockIdx.x * blockDim.x + threadIdx.x;
    if (i < n) p[i] = 0.f;
}

__global__ __launch_bounds__(128) void k_pool(
        const float* __restrict__ h, const int* __restrict__ batch,
        float* __restrict__ pooled, int N) {
    int c = threadIdx.x;
    int r0 = blockIdx.x * POOL_ROWS;
    if (r0 >= N) return;
    int rend = r0 + POOL_ROWS;
    if (rend > N) rend = N;
    int cur = batch[r0];
    float a = 0.f;
    for (int r = r0; r < rend; r++) {
        int b = batch[r];
        if (b != cur) {
            atomicAdd(&pooled[(size_t)cur * D + c], a);
            cur = b;
            a = 0.f;
        }
        a += h[(size_t)r * D + c];
    }
    atomicAdd(&pooled[(size_t)cur * D + c], a);
}

// ================= MLP head =================

__global__ __launch_bounds__(128) void k_head(
        const float* __restrict__ pooled,
        const float* __restrict__ W1, const float* __restrict__ b1,
        const float* __restrict__ W2, const float* __restrict__ b2,
        const float* __restrict__ W3, const float* __restrict__ b3,
        float* __restrict__ out) {
    __shared__ float v[D];
    __shared__ float z[D];
    __shared__ float red[D];
    int g = blockIdx.x;
    int t = threadIdx.x;

    v[t] = pooled[(size_t)g * D + t];
    __syncthreads();

    float s = b1[t];
    for (int k = 0; k < D; k++) s = fmaf(v[k], W1[(size_t)k * D + t], s);
    z[t] = fmaxf(s, 0.f);
    __syncthreads();

    s = b2[t];
    for (int k = 0; k < D; k++) s = fmaf(z[k], W2[(size_t)k * D + t], s);
    float z2 = fmaxf(s, 0.f);

    red[t] = z2 * W3[t];
    __syncthreads();
    for (int off = 64; off >= 1; off >>= 1) {
        if (t < off) red[t] += red[t + off];
        __syncthreads();
    }
    if (t == 0) out[g] = 1.f / (1.f + expf(-(red[0] + b3[0])));
}

// ================= orchestration =================

extern "C" void kernel_launch(void* const* d_in, const int* in_sizes, int n_in,
                              void* d_out, int out_size, void* d_ws, size_t ws_size,
                              hipStream_t stream) {
    const float* x     = (const float*)d_in[0];
    const int*   ei    = (const int*)d_in[1];
    const int*   batch = (const int*)d_in[2];
    const float* convW = (const float*)d_in[3];
    const float* convB = (const float*)d_in[4];
    const float* W1 = (const float*)d_in[5];
    const float* b1 = (const float*)d_in[6];
    const float* W2 = (const float*)d_in[7];
    const float* b2 = (const float*)d_in[8];
    const float* W3 = (const float*)d_in[9];
    const float* b3 = (const float*)d_in[10];
    float* out = (float*)d_out;

    const int N = in_sizes[0] / D;          // 100000
    const int E = in_sizes[1] / 2;          // 640000
    const int G = out_size;                 // 512
    const int NB = (N + 1023) / 1024;       // scan blocks

    // ---- workspace layout ----
    char* w = (char*)d_ws;
    size_t off = 0;
    auto alloc = [&](size_t bytes) -> char* {
        char* p = w + off;
        off += (bytes + 255) & ~(size_t)255;
        return p;
    };
    float* dinv   = (float*)alloc((size_t)N * 4);
    float* hws    = (float*)alloc((size_t)N * D * 4);
    float* bufA   = (float*)alloc((size_t)N * D * 4);
    float* pooled = (float*)alloc((size_t)G * D * 4);
    int*   counts = (int*)alloc((size_t)N * 4);
    int*   rowptr = (int*)alloc((size_t)(N + 1) * 4);
    int*   cursor = (int*)alloc((size_t)N * 4);
    int*   srcs   = (int*)alloc((size_t)E * 4);
    int*   bsums  = (int*)alloc((size_t)NB * 4);

    // ---- CSR build ----
    k_zero_int<<<(N + 255) / 256, 256, 0, stream>>>(counts, N);
    k_count<<<(E + 255) / 256, 256, 0, stream>>>(ei, counts, E);
    k_dinv<<<(N + 255) / 256, 256, 0, stream>>>(counts, dinv, N);
    k_scan1<<<NB, 256, 0, stream>>>(counts, rowptr, bsums, N);
    k_scan2<<<1, 128, 0, stream>>>(bsums, NB);
    k_scan3<<<(N + 1 + 255) / 256, 256, 0, stream>>>(rowptr, bsums, N);
    hipMemcpyAsync(cursor, rowptr, (size_t)N * 4, hipMemcpyDeviceToDevice, stream);
    k_fill<<<(E + 255) / 256, 256, 0, stream>>>(ei, cursor, srcs, E);

    // ---- 4 GCN layers ----
    const int gemm_grid = (N + 127) / 128;
    const int agg_grid  = (N + 3) / 4;      // 4 waves (nodes) per 256-thread block

    const float* hin = x;
    for (int l = 0; l < 4; l++) {
        k_gemm_mfma<<<gemm_grid, 256, 0, stream>>>(hin, convW + (size_t)l * D * D,
                                                   dinv, hws, N);
        k_agg<<<agg_grid, 256, 0, stream>>>(rowptr, srcs, hws, dinv,
                                            convB + (size_t)l * D, bufA, N);
        hin = bufA;
    }

    // ---- pooling + head ----
    k_zero<<<(G * D + 127) / 128, 128, 0, stream>>>(pooled, G * D);
    k_pool<<<(N + POOL_ROWS - 1) / POOL_ROWS, 128, 0, stream>>>(hin, batch, pooled, N);
    k_head<<<G, 128, 0, stream>>>(pooled, W1, b1, W2, b2, W3, b3, out);
}

// Round 4
// 518.249 us; speedup vs baseline: 9.2686x; 1.2274x over previous
//
#include <hip/hip_runtime.h>
#include <math.h>

#define D 128

typedef _Float16 half8 __attribute__((ext_vector_type(8)));
typedef _Float16 half2v __attribute__((ext_vector_type(2)));
typedef float f32x4 __attribute__((ext_vector_type(4)));

// ================= CSR build (counting sort by dst) =================

__global__ void k_zero_int(int* __restrict__ p, int n) {
    int i = blockIdx.x * blockDim.x + threadIdx.x;
    if (i < n) p[i] = 0;
}

__global__ void k_count(const int* __restrict__ ei, int* __restrict__ counts, int E) {
    int e = blockIdx.x * blockDim.x + threadIdx.x;
    if (e < E) atomicAdd(&counts[ei[E + e]], 1);   // dst row
}

__global__ void k_dinv(const int* __restrict__ counts, float* __restrict__ dinv, int N) {
    int i = blockIdx.x * blockDim.x + threadIdx.x;
    if (i < N) dinv[i] = rsqrtf((float)(counts[i] + 1));  // +1 self-loop
}

__global__ __launch_bounds__(256) void k_scan1(const int* __restrict__ counts,
                                               int* __restrict__ rowptr,
                                               int* __restrict__ bsums, int N) {
    __shared__ int sh[256];
    const int t = threadIdx.x;
    const int base = blockIdx.x * 1024 + t * 4;
    int c[4];
#pragma unroll
    for (int j = 0; j < 4; j++) c[j] = (base + j < N) ? counts[base + j] : 0;
    int tsum = c[0] + c[1] + c[2] + c[3];
    sh[t] = tsum;
    __syncthreads();
    for (int off = 1; off < 256; off <<= 1) {
        int v = (t >= off) ? sh[t - off] : 0;
        __syncthreads();
        sh[t] += v;
        __syncthreads();
    }
    int run = (t == 0) ? 0 : sh[t - 1];
    if (t == 255) bsums[blockIdx.x] = sh[255];
#pragma unroll
    for (int j = 0; j < 4; j++) {
        if (base + j <= N) rowptr[base + j] = run;
        run += c[j];
    }
}

__global__ __launch_bounds__(128) void k_scan2(int* __restrict__ bsums, int NB) {
    __shared__ int sh[128];
    const int t = threadIdx.x;
    sh[t] = (t < NB) ? bsums[t] : 0;
    __syncthreads();
    for (int off = 1; off < 128; off <<= 1) {
        int v = (t >= off) ? sh[t - off] : 0;
        __syncthreads();
        sh[t] += v;
        __syncthreads();
    }
    if (t < NB) bsums[t] = (t == 0) ? 0 : sh[t - 1];
}

__global__ void k_scan3(int* __restrict__ rowptr, const int* __restrict__ bsums, int N) {
    int i = blockIdx.x * blockDim.x + threadIdx.x;
    if (i <= N) rowptr[i] += bsums[i >> 10];
}

__global__ void k_fill(const int* __restrict__ ei, int* __restrict__ cursor,
                       int* __restrict__ srcs, int E) {
    int e = blockIdx.x * blockDim.x + threadIdx.x;
    if (e >= E) return;
    int pos = atomicAdd(&cursor[ei[E + e]], 1);
    srcs[pos] = ei[e];
}

// ================= GEMM: hws = fp16((H @ W) * dinv[row]), split-fp16 MFMA =================

__global__ __launch_bounds__(256) void k_gemm_mfma(
        const float* __restrict__ H, const float* __restrict__ W,
        const float* __restrict__ dinv, _Float16* __restrict__ hws, int N) {
    __shared__ _Float16 Bhi[32 * 64 * 8];   // 32 KB
    __shared__ _Float16 Blo[32 * 64 * 8];   // 32 KB

    const int tid  = threadIdx.x;
    const int w    = tid >> 6;
    const int lane = tid & 63;
    const int q    = lane >> 4;
    const int l16  = lane & 15;
    const int row0 = blockIdx.x * 128;

    for (int slot = tid; slot < 32 * 64; slot += 256) {
        int p = slot >> 6, l = slot & 63;
        int s = p >> 3, c = p & 7;
        int kbase = s * 32 + ((l >> 4) << 3);
        int n = (c << 4) + (l & 15);
        half8 hv, lv;
#pragma unroll
        for (int j = 0; j < 8; j++) {
            float wv = W[(size_t)(kbase + j) * D + n];
            _Float16 h = (_Float16)wv;
            hv[j] = h;
            lv[j] = (_Float16)(wv - (float)h);
        }
        *(half8*)(&Bhi[slot * 8]) = hv;
        *(half8*)(&Blo[slot * 8]) = lv;
    }
    __syncthreads();

    f32x4 acc[2][8];
#pragma unroll
    for (int t = 0; t < 2; t++)
#pragma unroll
        for (int c = 0; c < 8; c++) acc[t][c] = (f32x4){0.f, 0.f, 0.f, 0.f};

    const int rb0 = row0 + w * 32;

#pragma unroll
    for (int s = 0; s < 4; s++) {
        half8 ah[2], al[2];
#pragma unroll
        for (int t = 0; t < 2; t++) {
            int row = rb0 + t * 16 + l16;
            int rowc = row < N ? row : N - 1;
            const float* ap = H + (size_t)rowc * D + s * 32 + q * 8;
            float4 v0 = *(const float4*)(ap);
            float4 v1 = *(const float4*)(ap + 4);
            const float vv[8] = {v0.x, v0.y, v0.z, v0.w, v1.x, v1.y, v1.z, v1.w};
#pragma unroll
            for (int j = 0; j < 8; j++) {
                _Float16 h = (_Float16)vv[j];
                ah[t][j] = h;
                al[t][j] = (_Float16)(vv[j] - (float)h);
            }
        }
#pragma unroll
        for (int c = 0; c < 8; c++) {
            const int pb = ((s << 3) + c) * 512 + lane * 8;
            half8 bh = *(half8*)(&Bhi[pb]);
            half8 bl = *(half8*)(&Blo[pb]);
#pragma unroll
            for (int t = 0; t < 2; t++) {
                acc[t][c] = __builtin_amdgcn_mfma_f32_16x16x32_f16(al[t], bh, acc[t][c], 0, 0, 0);
                acc[t][c] = __builtin_amdgcn_mfma_f32_16x16x32_f16(ah[t], bl, acc[t][c], 0, 0, 0);
                acc[t][c] = __builtin_amdgcn_mfma_f32_16x16x32_f16(ah[t], bh, acc[t][c], 0, 0, 0);
            }
        }
    }

    float dv[2][4];
#pragma unroll
    for (int t = 0; t < 2; t++)
#pragma unroll
        for (int r = 0; r < 4; r++) {
            int row = rb0 + t * 16 + q * 4 + r;
            dv[t][r] = (row < N) ? dinv[row] : 0.f;
        }
#pragma unroll
    for (int t = 0; t < 2; t++) {
        int rbase = rb0 + t * 16 + q * 4;
#pragma unroll
        for (int c = 0; c < 8; c++) {
            int col = c * 16 + l16;
#pragma unroll
            for (int r = 0; r < 4; r++) {
                int row = rbase + r;
                if (row < N) hws[(size_t)row * D + col] = (_Float16)(acc[t][c][r] * dv[t][r]);
            }
        }
    }
}

// ====== aggregation: one wave per node, fp16 gathers, fp32 accumulate ======

__global__ __launch_bounds__(256) void k_agg(
        const int* __restrict__ rowptr, const int* __restrict__ srcs,
        const _Float16* __restrict__ hws, const float* __restrict__ dinv,
        const float* __restrict__ bias, float* __restrict__ hout, int N) {
    int wid = (blockIdx.x * blockDim.x + threadIdx.x) >> 6;   // node index
    if (wid >= N) return;
    int lane = threadIdx.x & 63;
    int c = lane * 2;

    int beg = rowptr[wid];
    int end = rowptr[wid + 1];

    half2v sv = *(const half2v*)(hws + (size_t)wid * D + c);   // self-loop term
    float ax0 = (float)sv[0], ay0 = (float)sv[1];
    float ax1 = 0.f, ay1 = 0.f, ax2 = 0.f, ay2 = 0.f, ax3 = 0.f, ay3 = 0.f;

    int e = beg;
    for (; e + 4 <= end; e += 4) {
        int s0 = srcs[e], s1 = srcs[e + 1], s2 = srcs[e + 2], s3 = srcs[e + 3];
        half2v v0 = *(const half2v*)(hws + (size_t)s0 * D + c);
        half2v v1 = *(const half2v*)(hws + (size_t)s1 * D + c);
        half2v v2 = *(const half2v*)(hws + (size_t)s2 * D + c);
        half2v v3 = *(const half2v*)(hws + (size_t)s3 * D + c);
        ax0 += (float)v0[0]; ay0 += (float)v0[1];
        ax1 += (float)v1[0]; ay1 += (float)v1[1];
        ax2 += (float)v2[0]; ay2 += (float)v2[1];
        ax3 += (float)v3[0]; ay3 += (float)v3[1];
    }
    for (; e < end; e++) {
        int s = srcs[e];
        half2v v = *(const half2v*)(hws + (size_t)s * D + c);
        ax0 += (float)v[0]; ay0 += (float)v[1];
    }
    ax0 += ax1 + ax2 + ax3;
    ay0 += ay1 + ay2 + ay3;

    float sc = dinv[wid];
    float2 b = *(const float2*)(bias + c);
    float2 o;
    o.x = fmaxf(fmaf(sc, ax0, b.x), 0.f);
    o.y = fmaxf(fmaf(sc, ay0, b.y), 0.f);
    *(float2*)(hout + (size_t)wid * D + c) = o;
}

// ========== fused pool + MLP head: one block (256 thr) per graph ==========
// batch is sorted: binary-search the graph's row range, 4 waves stride rows,
// LDS reduce, then the 3-layer head on threads 0..127.

__global__ __launch_bounds__(256) void k_poolhead(
        const float* __restrict__ h, const int* __restrict__ batch,
        const float* __restrict__ W1, const float* __restrict__ b1,
        const float* __restrict__ W2, const float* __restrict__ b2,
        const float* __restrict__ W3, const float* __restrict__ b3,
        float* __restrict__ out, int N) {
    __shared__ int sb[2];
    __shared__ float part[4][D];
    __shared__ float v[D];
    __shared__ float z[D];
    __shared__ float red[D];

    const int g = blockIdx.x;
    const int t = threadIdx.x;

    if (t < 2) {
        int target = g + t;
        int lo = 0, hi = N;
        while (lo < hi) {
            int mid = (lo + hi) >> 1;
            if (batch[mid] < target) lo = mid + 1; else hi = mid;
        }
        sb[t] = lo;
    }
    __syncthreads();
    const int rs = sb[0], re = sb[1];

    const int w = t >> 6;
    const int lane = t & 63;
    const int c = lane * 2;

    float ax = 0.f, ay = 0.f;
    for (int r = rs + w; r < re; r += 4) {
        float2 vv = *(const float2*)(h + (size_t)r * D + c);
        ax += vv.x; ay += vv.y;
    }
    part[w][c] = ax;
    part[w][c + 1] = ay;
    __syncthreads();

    if (t < D) v[t] = part[0][t] + part[1][t] + part[2][t] + part[3][t];
    __syncthreads();

    if (t < D) {
        float s = b1[t];
        for (int k = 0; k < D; k++) s = fmaf(v[k], W1[(size_t)k * D + t], s);
        z[t] = fmaxf(s, 0.f);
    }
    __syncthreads();

    if (t < D) {
        float s = b2[t];
        for (int k = 0; k < D; k++) s = fmaf(z[k], W2[(size_t)k * D + t], s);
        red[t] = fmaxf(s, 0.f) * W3[t];
    }
    __syncthreads();
    for (int off = 64; off >= 1; off >>= 1) {
        if (t < off) red[t] += red[t + off];
        __syncthreads();
    }
    if (t == 0) out[g] = 1.f / (1.f + expf(-(red[0] + b3[0])));
}

// ================= orchestration =================

extern "C" void kernel_launch(void* const* d_in, const int* in_sizes, int n_in,
                              void* d_out, int out_size, void* d_ws, size_t ws_size,
                              hipStream_t stream) {
    const float* x     = (const float*)d_in[0];
    const int*   ei    = (const int*)d_in[1];
    const int*   batch = (const int*)d_in[2];
    const float* convW = (const float*)d_in[3];
    const float* convB = (const float*)d_in[4];
    const float* W1 = (const float*)d_in[5];
    const float* b1 = (const float*)d_in[6];
    const float* W2 = (const float*)d_in[7];
    const float* b2 = (const float*)d_in[8];
    const float* W3 = (const float*)d_in[9];
    const float* b3 = (const float*)d_in[10];
    float* out = (float*)d_out;

    const int N = in_sizes[0] / D;          // 100000
    const int E = in_sizes[1] / 2;          // 640000
    const int G = out_size;                 // 512
    const int NB = (N + 1023) / 1024;

    // ---- workspace layout ----
    char* w = (char*)d_ws;
    size_t off = 0;
    auto alloc = [&](size_t bytes) -> char* {
        char* p = w + off;
        off += (bytes + 255) & ~(size_t)255;
        return p;
    };
    float*     dinv   = (float*)alloc((size_t)N * 4);
    _Float16*  hws    = (_Float16*)alloc((size_t)N * D * 2);
    float*     bufA   = (float*)alloc((size_t)N * D * 4);
    int*       counts = (int*)alloc((size_t)N * 4);
    int*       rowptr = (int*)alloc((size_t)(N + 1) * 4);
    int*       cursor = (int*)alloc((size_t)N * 4);
    int*       srcs   = (int*)alloc((size_t)E * 4);
    int*       bsums  = (int*)alloc((size_t)NB * 4);

    // ---- CSR build ----
    k_zero_int<<<(N + 255) / 256, 256, 0, stream>>>(counts, N);
    k_count<<<(E + 255) / 256, 256, 0, stream>>>(ei, counts, E);
    k_dinv<<<(N + 255) / 256, 256, 0, stream>>>(counts, dinv, N);
    k_scan1<<<NB, 256, 0, stream>>>(counts, rowptr, bsums, N);
    k_scan2<<<1, 128, 0, stream>>>(bsums, NB);
    k_scan3<<<(N + 1 + 255) / 256, 256, 0, stream>>>(rowptr, bsums, N);
    hipMemcpyAsync(cursor, rowptr, (size_t)N * 4, hipMemcpyDeviceToDevice, stream);
    k_fill<<<(E + 255) / 256, 256, 0, stream>>>(ei, cursor, srcs, E);

    // ---- 4 GCN layers ----
    const int gemm_grid = (N + 127) / 128;
    const int agg_grid  = (N + 3) / 4;

    const float* hin = x;
    for (int l = 0; l < 4; l++) {
        k_gemm_mfma<<<gemm_grid, 256, 0, stream>>>(hin, convW + (size_t)l * D * D,
                                                   dinv, hws, N);
        k_agg<<<agg_grid, 256, 0, stream>>>(rowptr, srcs, hws, dinv,
                                            convB + (size_t)l * D, bufA, N);
        hin = bufA;
    }

    // ---- fused pool + head ----
    k_poolhead<<<G, 256, 0, stream>>>(hin, batch, W1, b1, W2, b2, W3, b3, out, N);
}

// Round 5
// 506.320 us; speedup vs baseline: 9.4870x; 1.0236x over previous
//
#include <hip/hip_runtime.h>
#include <math.h>

#define D 128

typedef _Float16 half8 __attribute__((ext_vector_type(8)));
typedef _Float16 half2v __attribute__((ext_vector_type(2)));
typedef float f32x4 __attribute__((ext_vector_type(4)));

// ================= CSR build (counting sort by dst) =================

__global__ void k_count(const int* __restrict__ ei, int* __restrict__ counts, int E) {
    int e = blockIdx.x * blockDim.x + threadIdx.x;
    if (e < E) atomicAdd(&counts[ei[E + e]], 1);   // dst row
}

// scan over counts -> rowptr (exclusive), block sums out; also emits dinv = rsqrt(count+1)
__global__ __launch_bounds__(256) void k_scan1(const int* __restrict__ counts,
                                               int* __restrict__ rowptr,
                                               int* __restrict__ bsums,
                                               float* __restrict__ dinv, int N) {
    __shared__ int sh[256];
    const int t = threadIdx.x;
    const int base = blockIdx.x * 1024 + t * 4;
    int c[4];
#pragma unroll
    for (int j = 0; j < 4; j++) c[j] = (base + j < N) ? counts[base + j] : 0;
#pragma unroll
    for (int j = 0; j < 4; j++)
        if (base + j < N) dinv[base + j] = rsqrtf((float)(c[j] + 1));
    int tsum = c[0] + c[1] + c[2] + c[3];
    sh[t] = tsum;
    __syncthreads();
    for (int off = 1; off < 256; off <<= 1) {
        int v = (t >= off) ? sh[t - off] : 0;
        __syncthreads();
        sh[t] += v;
        __syncthreads();
    }
    int run = (t == 0) ? 0 : sh[t - 1];
    if (t == 255) bsums[blockIdx.x] = sh[255];
#pragma unroll
    for (int j = 0; j < 4; j++) {
        if (base + j <= N) rowptr[base + j] = run;
        run += c[j];
    }
}

__global__ __launch_bounds__(128) void k_scan2(int* __restrict__ bsums, int NB) {
    __shared__ int sh[128];
    const int t = threadIdx.x;
    sh[t] = (t < NB) ? bsums[t] : 0;
    __syncthreads();
    for (int off = 1; off < 128; off <<= 1) {
        int v = (t >= off) ? sh[t - off] : 0;
        __syncthreads();
        sh[t] += v;
        __syncthreads();
    }
    if (t < NB) bsums[t] = (t == 0) ? 0 : sh[t - 1];
}

__global__ void k_scan3(int* __restrict__ rowptr, const int* __restrict__ bsums, int N) {
    int i = blockIdx.x * blockDim.x + threadIdx.x;
    if (i <= N) rowptr[i] += bsums[i >> 10];
}

__global__ void k_fill(const int* __restrict__ ei, int* __restrict__ cursor,
                       int* __restrict__ srcs, int E) {
    int e = blockIdx.x * blockDim.x + threadIdx.x;
    if (e >= E) return;
    int pos = atomicAdd(&cursor[ei[E + e]], 1);
    srcs[pos] = ei[e];
}

// ================= x -> fp16 =================

__global__ void k_cvt(const float* __restrict__ x, _Float16* __restrict__ y, int n8) {
    int i = blockIdx.x * blockDim.x + threadIdx.x;
    if (i >= n8) return;
    const float4 v0 = *(const float4*)(x + (size_t)i * 8);
    const float4 v1 = *(const float4*)(x + (size_t)i * 8 + 4);
    half8 h;
    h[0] = (_Float16)v0.x; h[1] = (_Float16)v0.y; h[2] = (_Float16)v0.z; h[3] = (_Float16)v0.w;
    h[4] = (_Float16)v1.x; h[5] = (_Float16)v1.y; h[6] = (_Float16)v1.z; h[7] = (_Float16)v1.w;
    *(half8*)(y + (size_t)i * 8) = h;
}

// ====== GEMM: hws = fp16((H16 @ W) * dinv[row]) — fp16 A direct, B hi/lo split ======
// Block: 256 thr (4 waves), M-tile 128; wave = 32 rows (2x 16-row tiles) x 8 col-tiles.

__global__ __launch_bounds__(256) void k_gemm_mfma(
        const _Float16* __restrict__ H16, const float* __restrict__ W,
        const float* __restrict__ dinv, _Float16* __restrict__ hws, int N) {
    __shared__ _Float16 Bhi[32 * 64 * 8];   // 32 KB, fragment-packed
    __shared__ _Float16 Blo[32 * 64 * 8];   // 32 KB

    const int tid  = threadIdx.x;
    const int w    = tid >> 6;
    const int lane = tid & 63;
    const int q    = lane >> 4;
    const int l16  = lane & 15;
    const int row0 = blockIdx.x * 128;

    // stage B (hi/lo split, fragment order -> conflict-free b128 reads)
    for (int slot = tid; slot < 32 * 64; slot += 256) {
        int p = slot >> 6, l = slot & 63;
        int s = p >> 3, c = p & 7;
        int kbase = s * 32 + ((l >> 4) << 3);
        int n = (c << 4) + (l & 15);
        half8 hv, lv;
#pragma unroll
        for (int j = 0; j < 8; j++) {
            float wv = W[(size_t)(kbase + j) * D + n];
            _Float16 h = (_Float16)wv;
            hv[j] = h;
            lv[j] = (_Float16)(wv - (float)h);
        }
        *(half8*)(&Bhi[slot * 8]) = hv;
        *(half8*)(&Blo[slot * 8]) = lv;
    }
    __syncthreads();

    f32x4 acc[2][8];
#pragma unroll
    for (int t = 0; t < 2; t++)
#pragma unroll
        for (int c = 0; c < 8; c++) acc[t][c] = (f32x4){0.f, 0.f, 0.f, 0.f};

    const int rb0 = row0 + w * 32;

#pragma unroll
    for (int s = 0; s < 4; s++) {
        half8 a[2];
#pragma unroll
        for (int t = 0; t < 2; t++) {
            int row = rb0 + t * 16 + l16;
            int rowc = row < N ? row : N - 1;
            a[t] = *(const half8*)(H16 + (size_t)rowc * D + s * 32 + q * 8);  // 16 B
        }
#pragma unroll
        for (int c = 0; c < 8; c++) {
            const int pb = ((s << 3) + c) * 512 + lane * 8;
            half8 bh = *(half8*)(&Bhi[pb]);
            half8 bl = *(half8*)(&Blo[pb]);
#pragma unroll
            for (int t = 0; t < 2; t++) {
                acc[t][c] = __builtin_amdgcn_mfma_f32_16x16x32_f16(a[t], bl, acc[t][c], 0, 0, 0);
                acc[t][c] = __builtin_amdgcn_mfma_f32_16x16x32_f16(a[t], bh, acc[t][c], 0, 0, 0);
            }
        }
    }

    // epilogue: C/D col=l16, row=q*4+reg; scale by dinv[row], store fp16
    float dv[2][4];
#pragma unroll
    for (int t = 0; t < 2; t++)
#pragma unroll
        for (int r = 0; r < 4; r++) {
            int row = rb0 + t * 16 + q * 4 + r;
            dv[t][r] = (row < N) ? dinv[row] : 0.f;
        }
#pragma unroll
    for (int t = 0; t < 2; t++) {
        int rbase = rb0 + t * 16 + q * 4;
#pragma unroll
        for (int c = 0; c < 8; c++) {
            int col = c * 16 + l16;
#pragma unroll
            for (int r = 0; r < 4; r++) {
                int row = rbase + r;
                if (row < N) hws[(size_t)row * D + col] = (_Float16)(acc[t][c][r] * dv[t][r]);
            }
        }
    }
}

// ====== aggregation: one wave per node, fp16 gathers, fp32 accumulate, fp16 out ======

__global__ __launch_bounds__(256) void k_agg(
        const int* __restrict__ rowptr, const int* __restrict__ srcs,
        const _Float16* __restrict__ hws, const float* __restrict__ dinv,
        const float* __restrict__ bias, _Float16* __restrict__ hout, int N) {
    int wid = (blockIdx.x * blockDim.x + threadIdx.x) >> 6;   // node index
    if (wid >= N) return;
    int lane = threadIdx.x & 63;
    int c = lane * 2;

    int beg = rowptr[wid];
    int end = rowptr[wid + 1];

    half2v sv = *(const half2v*)(hws + (size_t)wid * D + c);   // self-loop term
    float ax0 = (float)sv[0], ay0 = (float)sv[1];
    float ax1 = 0.f, ay1 = 0.f, ax2 = 0.f, ay2 = 0.f, ax3 = 0.f, ay3 = 0.f;

    int e = beg;
    for (; e + 4 <= end; e += 4) {
        int s0 = srcs[e], s1 = srcs[e + 1], s2 = srcs[e + 2], s3 = srcs[e + 3];
        half2v v0 = *(const half2v*)(hws + (size_t)s0 * D + c);
        half2v v1 = *(const half2v*)(hws + (size_t)s1 * D + c);
        half2v v2 = *(const half2v*)(hws + (size_t)s2 * D + c);
        half2v v3 = *(const half2v*)(hws + (size_t)s3 * D + c);
        ax0 += (float)v0[0]; ay0 += (float)v0[1];
        ax1 += (float)v1[0]; ay1 += (float)v1[1];
        ax2 += (float)v2[0]; ay2 += (float)v2[1];
        ax3 += (float)v3[0]; ay3 += (float)v3[1];
    }
    for (; e < end; e++) {
        int s = srcs[e];
        half2v v = *(const half2v*)(hws + (size_t)s * D + c);
        ax0 += (float)v[0]; ay0 += (float)v[1];
    }
    ax0 += ax1 + ax2 + ax3;
    ay0 += ay1 + ay2 + ay3;

    float sc = dinv[wid];
    float2 b = *(const float2*)(bias + c);
    half2v o;
    o[0] = (_Float16)fmaxf(fmaf(sc, ax0, b.x), 0.f);
    o[1] = (_Float16)fmaxf(fmaf(sc, ay0, b.y), 0.f);
    *(half2v*)(hout + (size_t)wid * D + c) = o;
}

// ========== fused pool + MLP head: one block (256 thr) per graph ==========

__global__ __launch_bounds__(256) void k_poolhead(
        const _Float16* __restrict__ h, const int* __restrict__ batch,
        const float* __restrict__ W1, const float* __restrict__ b1,
        const float* __restrict__ W2, const float* __restrict__ b2,
        const float* __restrict__ W3, const float* __restrict__ b3,
        float* __restrict__ out, int N) {
    __shared__ int sb[2];
    __shared__ float part[4][D];
    __shared__ float v[D];
    __shared__ float z[D];
    __shared__ float red[D];

    const int g = blockIdx.x;
    const int t = threadIdx.x;

    if (t < 2) {
        int target = g + t;
        int lo = 0, hi = N;
        while (lo < hi) {
            int mid = (lo + hi) >> 1;
            if (batch[mid] < target) lo = mid + 1; else hi = mid;
        }
        sb[t] = lo;
    }
    __syncthreads();
    const int rs = sb[0], re = sb[1];

    const int w = t >> 6;
    const int lane = t & 63;
    const int c = lane * 2;

    float ax = 0.f, ay = 0.f;
    for (int r = rs + w; r < re; r += 4) {
        half2v vv = *(const half2v*)(h + (size_t)r * D + c);
        ax += (float)vv[0]; ay += (float)vv[1];
    }
    part[w][c] = ax;
    part[w][c + 1] = ay;
    __syncthreads();

    if (t < D) v[t] = part[0][t] + part[1][t] + part[2][t] + part[3][t];
    __syncthreads();

    if (t < D) {
        float s = b1[t];
        for (int k = 0; k < D; k++) s = fmaf(v[k], W1[(size_t)k * D + t], s);
        z[t] = fmaxf(s, 0.f);
    }
    __syncthreads();

    if (t < D) {
        float s = b2[t];
        for (int k = 0; k < D; k++) s = fmaf(z[k], W2[(size_t)k * D + t], s);
        red[t] = fmaxf(s, 0.f) * W3[t];
    }
    __syncthreads();
    for (int off = 64; off >= 1; off >>= 1) {
        if (t < off) red[t] += red[t + off];
        __syncthreads();
    }
    if (t == 0) out[g] = 1.f / (1.f + expf(-(red[0] + b3[0])));
}

// ================= orchestration =================

extern "C" void kernel_launch(void* const* d_in, const int* in_sizes, int n_in,
                              void* d_out, int out_size, void* d_ws, size_t ws_size,
                              hipStream_t stream) {
    const float* x     = (const float*)d_in[0];
    const int*   ei    = (const int*)d_in[1];
    const int*   batch = (const int*)d_in[2];
    const float* convW = (const float*)d_in[3];
    const float* convB = (const float*)d_in[4];
    const float* W1 = (const float*)d_in[5];
    const float* b1 = (const float*)d_in[6];
    const float* W2 = (const float*)d_in[7];
    const float* b2 = (const float*)d_in[8];
    const float* W3 = (const float*)d_in[9];
    const float* b3 = (const float*)d_in[10];
    float* out = (float*)d_out;

    const int N = in_sizes[0] / D;          // 100000
    const int E = in_sizes[1] / 2;          // 640000
    const int G = out_size;                 // 512
    const int NB = (N + 1023) / 1024;

    // ---- workspace layout ----
    char* w = (char*)d_ws;
    size_t off = 0;
    auto alloc = [&](size_t bytes) -> char* {
        char* p = w + off;
        off += (bytes + 255) & ~(size_t)255;
        return p;
    };
    float*     dinv   = (float*)alloc((size_t)N * 4);
    _Float16*  x16    = (_Float16*)alloc((size_t)N * D * 2);
    _Float16*  hws    = (_Float16*)alloc((size_t)N * D * 2);
    _Float16*  hbuf   = (_Float16*)alloc((size_t)N * D * 2);
    int*       counts = (int*)alloc((size_t)N * 4);
    int*       rowptr = (int*)alloc((size_t)(N + 1) * 4);
    int*       cursor = (int*)alloc((size_t)N * 4);
    int*       srcs   = (int*)alloc((size_t)E * 4);
    int*       bsums  = (int*)alloc((size_t)NB * 4);

    // ---- CSR build + input convert ----
    hipMemsetAsync(counts, 0, (size_t)N * 4, stream);
    k_count<<<(E + 255) / 256, 256, 0, stream>>>(ei, counts, E);
    k_cvt<<<(N * D / 8 + 255) / 256, 256, 0, stream>>>(x, x16, N * D / 8);
    k_scan1<<<NB, 256, 0, stream>>>(counts, rowptr, bsums, dinv, N);
    k_scan2<<<1, 128, 0, stream>>>(bsums, NB);
    k_scan3<<<(N + 1 + 255) / 256, 256, 0, stream>>>(rowptr, bsums, N);
    hipMemcpyAsync(cursor, rowptr, (size_t)N * 4, hipMemcpyDeviceToDevice, stream);
    k_fill<<<(E + 255) / 256, 256, 0, stream>>>(ei, cursor, srcs, E);

    // ---- 4 GCN layers ----
    const int gemm_grid = (N + 127) / 128;
    const int agg_grid  = (N + 3) / 4;

    const _Float16* hin = x16;
    for (int l = 0; l < 4; l++) {
        k_gemm_mfma<<<gemm_grid, 256, 0, stream>>>(hin, convW + (size_t)l * D * D,
                                                   dinv, hws, N);
        k_agg<<<agg_grid, 256, 0, stream>>>(rowptr, srcs, hws, dinv,
                                            convB + (size_t)l * D, hbuf, N);
        hin = hbuf;
    }

    // ---- fused pool + head ----
    k_poolhead<<<G, 256, 0, stream>>>(hin, batch, W1, b1, W2, b2, W3, b3, out, N);
}